// Round 7
// baseline (448.733 us; speedup 1.0000x reference)
//
#include <hip/hip_runtime.h>
#include <math.h>

// _p,_q are (8192, 4096) f32. weuc = sum_rows sqrt( sum_j (p-q)^2 * jsd_j ).
constexpr int ROWS   = 8192;
constexpr int COLS   = 4096;
constexpr int TPB    = 256;            // 4 waves/block, one ROW PER WAVE, no barriers
constexpr int WPB    = TPB / 64;
constexpr int CHUNKS = COLS / (64 * 4);  // 16 float4 chunks per lane

__device__ __forceinline__ float wave_sum(float v) {
    #pragma unroll
    for (int o = 32; o > 0; o >>= 1) v += __shfl_xor(v, o, 64);
    return v;
}

// One row per wave. Row-pair (32 KB) lives entirely in this wave's registers.
// No LDS, no __syncthreads -> no forced vmcnt(0) drains; waves overlap freely.
__global__ __launch_bounds__(TPB, 3) void wjs_row_kernel(const float* __restrict__ P,
                                                         const float* __restrict__ Q,
                                                         float* __restrict__ rowres) {
    const int lane = threadIdx.x & 63;
    const int wid  = threadIdx.x >> 6;
    const int row  = blockIdx.x * WPB + wid;

    const float4* __restrict__ p4 = reinterpret_cast<const float4*>(P + (size_t)row * COLS);
    const float4* __restrict__ q4 = reinterpret_cast<const float4*>(Q + (size_t)row * COLS);

    // Coalesced: chunk c, lane l -> float4 index c*64+l (wave reads 1 KB contiguous).
    float4 vp[CHUNKS], vq[CHUNKS];
    #pragma unroll
    for (int c = 0; c < CHUNKS; ++c) {
        vp[c] = p4[c * 64 + lane];
        vq[c] = q4[c * 64 + lane];
    }

    // Pass 1: row maxima (register-local, then 6-step butterfly).
    float mp = -INFINITY, mq = -INFINITY;
    #pragma unroll
    for (int c = 0; c < CHUNKS; ++c) {
        mp = fmaxf(mp, fmaxf(fmaxf(vp[c].x, vp[c].y), fmaxf(vp[c].z, vp[c].w)));
        mq = fmaxf(mq, fmaxf(fmaxf(vq[c].x, vq[c].y), fmaxf(vq[c].z, vq[c].w)));
    }
    #pragma unroll
    for (int o = 32; o > 0; o >>= 1) {
        mp = fmaxf(mp, __shfl_xor(mp, o, 64));
        mq = fmaxf(mq, __shfl_xor(mq, o, 64));
    }

    // Pass 2: softmax denominators.
    float sp = 0.0f, sq = 0.0f;
    #pragma unroll
    for (int c = 0; c < CHUNKS; ++c) {
        sp += __expf(vp[c].x - mp) + __expf(vp[c].y - mp)
            + __expf(vp[c].z - mp) + __expf(vp[c].w - mp);
        sq += __expf(vq[c].x - mq) + __expf(vq[c].y - mq)
            + __expf(vq[c].z - mq) + __expf(vq[c].w - mq);
    }
    sp = wave_sum(sp);
    sq = wave_sum(sq);

    const float inv_sp = 1.0f / sp;
    const float inv_sq = 1.0f / sq;
    const float lsp = __logf(sp);
    const float lsq = __logf(sq);

    // Pass 3: JSD-weighted squared distance. exp recomputed (regs too tight to store).
    // log p_j = (x_j - max) - log(sum): no per-element log for p,q; one log for m.
    float acc = 0.0f;
    #pragma unroll
    for (int c = 0; c < CHUNKS; ++c) {
        const float xps[4] = {vp[c].x, vp[c].y, vp[c].z, vp[c].w};
        const float xqs[4] = {vq[c].x, vq[c].y, vq[c].z, vq[c].w};
        #pragma unroll
        for (int k = 0; k < 4; ++k) {
            const float tp = xps[k] - mp;              // ln of unnorm p
            const float tq = xqs[k] - mq;
            const float p  = __expf(tp) * inv_sp;
            const float q  = __expf(tq) * inv_sq;
            const float m  = 0.5f * (p + q);
            const float lm = __logf(m);
            const float lp = tp - lsp;
            const float lq = tq - lsq;
            const float jsd = 0.5f * (q * (lq - lm) + p * (lp - lm));
            const float d = xps[k] - xqs[k];
            acc = fmaf(d * d, jsd, acc);
        }
    }
    acc = wave_sum(acc);
    if (lane == 0)
        rowres[row] = sqrtf(fmaxf(acc, 0.0f));   // clamp rounding negatives

}

// Deterministic final sum over 8192 per-row results. Fully writes d_out.
__global__ __launch_bounds__(1024) void wjs_final_kernel(const float* __restrict__ rowres,
                                                         float* __restrict__ out) {
    __shared__ float smem[16];
    const int tid = threadIdx.x;
    float acc = 0.0f;
    for (int i = tid; i < ROWS; i += 1024) acc += rowres[i];
    acc = wave_sum(acc);
    const int wid = tid >> 6, lane = tid & 63;
    if (lane == 0) smem[wid] = acc;
    __syncthreads();
    if (wid == 0) {
        float x = (lane < 16) ? smem[lane] : 0.0f;
        x = wave_sum(x);
        if (lane == 0) out[0] = x;
    }
}

extern "C" void kernel_launch(void* const* d_in, const int* in_sizes, int n_in,
                              void* d_out, int out_size, void* d_ws, size_t ws_size,
                              hipStream_t stream) {
    const float* P = (const float*)d_in[0];
    const float* Q = (const float*)d_in[1];
    float* rowres  = (float*)d_ws;        // 8192 floats = 32 KB scratch
    float* out     = (float*)d_out;

    wjs_row_kernel<<<ROWS / WPB, TPB, 0, stream>>>(P, Q, rowres);
    wjs_final_kernel<<<1, 1024, 0, stream>>>(rowres, out);
}